// Round 6
// baseline (155.563 us; speedup 1.0000x reference)
//
#include <hip/hip_runtime.h>
#include <hip/hip_bf16.h>
#include <float.h>

#define NN 50000
#define KNB 32
#define INC 128
#define HC 64
#define EDD 32
#define H2C 128
#define NBLK 782   // ceil(50000/64)

typedef __attribute__((ext_vector_type(8))) short bf16x8;
typedef __attribute__((ext_vector_type(4))) float f32x4;

__device__ __forceinline__ short f2bf(float f) {
    unsigned u = __builtin_bit_cast(unsigned, f);
    u += 0x7fffu + ((u >> 16) & 1u);          // RTNE
    return (short)(u >> 16);
}
__device__ __forceinline__ float bf2f(short h) {
    unsigned u = ((unsigned)(unsigned short)h) << 16;
    return __builtin_bit_cast(float, u);
}

// ---------------------------------------------------------------------------
// K0: pre-convert weights to fragment-ordered bf16 buffers.
// ---------------------------------------------------------------------------
__global__ __launch_bounds__(256) void k_prep(
    const float* __restrict__ w_src, const float* __restrict__ w_dst,
    const float* __restrict__ w1, const float* __restrict__ w2,
    const float* __restrict__ w_edge,
    short* __restrict__ pAhi, short* __restrict__ pAlo,
    short* __restrict__ p1hi, short* __restrict__ p1lo,
    short* __restrict__ p2hi, short* __restrict__ p2lo,
    short* __restrict__ pE)
{
    const int tid = blockIdx.x * 256 + threadIdx.x;
    const int nT  = gridDim.x * 256;
    for (int idx = tid; idx < 16384; idx += nT) {
        int kt = (idx >> 12) & 3, nt = (idx >> 9) & 7, lane = (idx >> 3) & 63, j = idx & 7;
        int lr = lane & 15, lg = lane >> 4;
        int ch = nt * 16 + lr, k = kt * 32 + lg * 8 + j;
        float f = (ch < 64) ? w_src[ch * 128 + k] : w_dst[(ch - 64) * 128 + k];
        short hi = f2bf(f);
        pAhi[idx] = hi; pAlo[idx] = f2bf(f - bf2f(hi));
    }
    for (int idx = tid; idx < 8192; idx += nT) {
        int kt = (idx >> 12) & 1, nt = (idx >> 9) & 7, lane = (idx >> 3) & 63, j = idx & 7;
        int lr = lane & 15, lg = lane >> 4;
        int ch = nt * 16 + lr, k = kt * 32 + lg * 8 + j;
        float f = w1[ch * 64 + k];
        short hi = f2bf(f);
        p1hi[idx] = hi; p1lo[idx] = f2bf(f - bf2f(hi));
    }
    for (int idx = tid; idx < 8192; idx += nT) {
        int kt = (idx >> 11) & 3, nt = (idx >> 9) & 3, lane = (idx >> 3) & 63, j = idx & 7;
        int lr = lane & 15, lg = lane >> 4;
        int ch = nt * 16 + lr, k = kt * 32 + lg * 8 + j;
        float f = w2[ch * 128 + k];
        short hi = f2bf(f);
        p2hi[idx] = hi; p2lo[idx] = f2bf(f - bf2f(hi));
    }
    for (int idx = tid; idx < 2048; idx += nT) {
        int nt = (idx >> 9) & 3, lane = (idx >> 3) & 63, j = idx & 7;
        int lr = lane & 15, lg = lane >> 4;
        int ch = nt * 16 + lr, k = lg * 8 + j;
        pE[idx] = f2bf(w_edge[ch * EDD + k]);
    }
}

__device__ __forceinline__ void split8(const float* av, bf16x8& ahi, bf16x8& alo) {
    #pragma unroll
    for (int j = 0; j < 8; ++j) {
        short h = f2bf(av[j]);
        ahi[j] = h;
        alo[j] = f2bf(av[j] - bf2f(h));
    }
}

// ---------------------------------------------------------------------------
// K1 (MFMA): [srcP|dstf] = x @ [w_src;w_dst].T ; srcP stored permuted:
// srcP[node*64 + lr*4 + nt] = src_ch[nt*16+lr]
// ---------------------------------------------------------------------------
__global__ __launch_bounds__(256) void k_lin1(
    const float* __restrict__ x, const short* __restrict__ pAhi,
    const short* __restrict__ pAlo, float* __restrict__ srcP,
    float* __restrict__ dstf)
{
    const int lane = threadIdx.x & 63, wave = threadIdx.x >> 6;
    const int lr = lane & 15, lg = lane >> 4;
    const int nb = blockIdx.x * 64 + wave * 16;
    const bf16x8* Bh = (const bf16x8*)pAhi;
    const bf16x8* Bl = (const bf16x8*)pAlo;
    int row = nb + lr; if (row > NN - 1) row = NN - 1;

    f32x4 acc[8];
    #pragma unroll
    for (int i = 0; i < 8; ++i) acc[i] = (f32x4){0.f, 0.f, 0.f, 0.f};

    #pragma unroll
    for (int kt = 0; kt < 4; ++kt) {
        const float* ap = x + (size_t)row * INC + kt * 32 + lg * 8;
        float4 a0 = *(const float4*)ap, a1 = *(const float4*)(ap + 4);
        float av[8] = {a0.x, a0.y, a0.z, a0.w, a1.x, a1.y, a1.z, a1.w};
        bf16x8 ahi, alo;
        split8(av, ahi, alo);
        #pragma unroll
        for (int nt = 0; nt < 8; ++nt) {
            bf16x8 bh = Bh[(kt * 8 + nt) * 64 + lane];
            bf16x8 bl = Bl[(kt * 8 + nt) * 64 + lane];
            acc[nt] = __builtin_amdgcn_mfma_f32_16x16x32_bf16(ahi, bl, acc[nt], 0, 0, 0);
            acc[nt] = __builtin_amdgcn_mfma_f32_16x16x32_bf16(alo, bh, acc[nt], 0, 0, 0);
            acc[nt] = __builtin_amdgcn_mfma_f32_16x16x32_bf16(ahi, bh, acc[nt], 0, 0, 0);
        }
    }
    #pragma unroll
    for (int nt = 0; nt < 8; ++nt)
        #pragma unroll
        for (int q = 0; q < 4; ++q) {
            int node = nb + lg * 4 + q;
            if (node < NN) {
                float v = acc[nt][q];
                if (nt < 4) srcP[node * HC + lr * 4 + nt] = v;     // permuted
                else        dstf[node * HC + (nt - 4) * 16 + lr] = v;
            }
        }
}

// ---------------------------------------------------------------------------
// K2 (MFMA, 2-node pipelined): edge projection + ReLU+eps + softmax agg.
// One wave = 2 nodes; node1's loads issue before node0's softmax so each
// node's memory latency hides under the other's compute. No max-subtract
// (softmax shift-invariant; msg bounded ~11, exp safe in fp32).
// ---------------------------------------------------------------------------
__global__ __launch_bounds__(256) void k_edge_agg_mfma(
    const float* __restrict__ srcP, const float* __restrict__ dstf,
    const float* __restrict__ edge_attr, const short* __restrict__ pE,
    const int* __restrict__ esrc, const int* __restrict__ nbr,
    float* __restrict__ outf)
{
    const int lane = threadIdx.x & 63;
    const int wave = threadIdx.x >> 6;
    const int n0   = (blockIdx.x * 4 + wave) * 2;   // grid 6250*4*2 = 50000
    const int n1   = n0 + 1;
    const int lr = lane & 15, lg = lane >> 4;

    // ---- phase 0: issue all independent loads for BOTH nodes ----
    int4 s00 = *(const int4*)&esrc[n0 * KNB + lg * 4];
    int4 s01 = *(const int4*)&esrc[n0 * KNB + 16 + lg * 4];
    int4 s10 = *(const int4*)&esrc[n1 * KNB + lg * 4];
    int4 s11 = *(const int4*)&esrc[n1 * KNB + 16 + lg * 4];
    int nbv0 = nbr[n0 * KNB + (lane & 31)];
    int nbv1 = nbr[n1 * KNB + (lane & 31)];
    float d0 = dstf[n0 * HC + lane];
    float d1 = dstf[n1 * HC + lane];

    const bf16x8* Bp = (const bf16x8*)pE;
    bf16x8 bfrag[4];
    #pragma unroll
    for (int nt = 0; nt < 4; ++nt) bfrag[nt] = Bp[nt * 64 + lane];

    // attr tiles: 4 x float4 per node per lane
    const float* ab0 = edge_attr + (size_t)n0 * KNB * EDD;
    const float* ab1 = edge_attr + (size_t)n1 * KNB * EDD;
    float4 at0[4], at1[4];
    #pragma unroll
    for (int mt = 0; mt < 2; ++mt) {
        at0[mt * 2]     = *(const float4*)(ab0 + (mt * 16 + lr) * EDD + lg * 8);
        at0[mt * 2 + 1] = *(const float4*)(ab0 + (mt * 16 + lr) * EDD + lg * 8 + 4);
        at1[mt * 2]     = *(const float4*)(ab1 + (mt * 16 + lr) * EDD + lg * 8);
        at1[mt * 2 + 1] = *(const float4*)(ab1 + (mt * 16 + lr) * EDD + lg * 8 + 4);
    }

    // ---- phase 1: gathers for both nodes (dep: esrc) ----
    int i00[4] = {s00.x, s00.y, s00.z, s00.w};
    int i01[4] = {s01.x, s01.y, s01.z, s01.w};
    int i10[4] = {s10.x, s10.y, s10.z, s10.w};
    int i11[4] = {s11.x, s11.y, s11.z, s11.w};
    float4 xj0[2][4], xj1[2][4];
    #pragma unroll
    for (int r = 0; r < 4; ++r) {
        xj0[0][r] = *(const float4*)&srcP[(size_t)i00[r] * HC + lr * 4];
        xj0[1][r] = *(const float4*)&srcP[(size_t)i01[r] * HC + lr * 4];
    }
    #pragma unroll
    for (int r = 0; r < 4; ++r) {
        xj1[0][r] = *(const float4*)&srcP[(size_t)i10[r] * HC + lr * 4];
        xj1[1][r] = *(const float4*)&srcP[(size_t)i11[r] * HC + lr * 4];
    }

    unsigned long long bm0 = __ballot((lane < 32) && (nbv0 >= 0));
    unsigned long long bm1 = __ballot((lane < 32) && (nbv1 >= 0));
    unsigned vm0 = (unsigned)bm0, vm1 = (unsigned)bm1;

    float out0, out1;
    #pragma unroll
    for (int node = 0; node < 2; ++node) {
        const float4* at = node ? at1 : at0;
        const float4 (*xj)[4] = node ? xj1 : xj0;
        unsigned vmask = node ? vm1 : vm0;

        // convert attr -> A fragments
        bf16x8 afrag[2];
        #pragma unroll
        for (int mt = 0; mt < 2; ++mt) {
            float av[8] = {at[mt*2].x, at[mt*2].y, at[mt*2].z, at[mt*2].w,
                           at[mt*2+1].x, at[mt*2+1].y, at[mt*2+1].z, at[mt*2+1].w};
            bf16x8 lo;
            split8(av, afrag[mt], lo);
            (void)lo;
        }

        // projection
        f32x4 p[2][4];
        #pragma unroll
        for (int mt = 0; mt < 2; ++mt)
            #pragma unroll
            for (int nt = 0; nt < 4; ++nt) {
                f32x4 z = {0.f, 0.f, 0.f, 0.f};
                p[mt][nt] = __builtin_amdgcn_mfma_f32_16x16x32_bf16(
                    afrag[mt], bfrag[nt], z, 0, 0, 0);
            }

        // fused msg/exp/accumulate per output tile (no max-subtract)
        float res[4];
        #pragma unroll
        for (int nt = 0; nt < 4; ++nt) {
            float se = 0.f, ws = 0.f;
            #pragma unroll
            for (int mt = 0; mt < 2; ++mt)
                #pragma unroll
                for (int r = 0; r < 4; ++r) {
                    float xjv = (nt == 0) ? xj[mt][r].x : (nt == 1) ? xj[mt][r].y
                              : (nt == 2) ? xj[mt][r].z : xj[mt][r].w;
                    float m = fmaxf(p[mt][nt][r] + xjv, 0.f) + 1e-7f;
                    int k = mt * 16 + lg * 4 + r;
                    float a = ((vmask >> k) & 1u) ? m : -FLT_MAX;
                    float t = __expf(a);
                    se += t;
                    ws = fmaf(m, t, ws);
                }
            se += __shfl_xor(se, 16, 64); ws += __shfl_xor(ws, 16, 64);
            se += __shfl_xor(se, 32, 64); ws += __shfl_xor(ws, 32, 64);
            res[nt] = ws / (se + 1e-16f);
        }

        float r01 = (lg & 1) ? res[1] : res[0];
        float r23 = (lg & 1) ? res[3] : res[2];
        float rr  = (lg & 2) ? r23 : r01;
        if (node == 0) out0 = rr; else out1 = rr;
    }

    outf[n0 * HC + lane] = out0 + d0;
    outf[n1 * HC + lane] = out1 + d1;
}

// ---------------------------------------------------------------------------
// K3 (MFMA): h = out @ w1.T  [N,64]->[N,128]  + per-block BN partials.
// ---------------------------------------------------------------------------
__global__ __launch_bounds__(256) void k_lin2(
    const float* __restrict__ outf, const short* __restrict__ p1hi,
    const short* __restrict__ p1lo, float* __restrict__ h,
    float* __restrict__ partials)
{
    __shared__ float ps[128 * 16], pq[128 * 16];
    const int t = threadIdx.x;
    const int lane = t & 63, wave = t >> 6;
    const int lr = lane & 15, lg = lane >> 4;
    const int nb = blockIdx.x * 64 + wave * 16;
    const bf16x8* Bh = (const bf16x8*)p1hi;
    const bf16x8* Bl = (const bf16x8*)p1lo;
    int row = nb + lr; if (row > NN - 1) row = NN - 1;

    f32x4 acc[8];
    #pragma unroll
    for (int i = 0; i < 8; ++i) acc[i] = (f32x4){0.f, 0.f, 0.f, 0.f};

    #pragma unroll
    for (int kt = 0; kt < 2; ++kt) {
        const float* ap = outf + (size_t)row * HC + kt * 32 + lg * 8;
        float4 a0 = *(const float4*)ap, a1 = *(const float4*)(ap + 4);
        float av[8] = {a0.x, a0.y, a0.z, a0.w, a1.x, a1.y, a1.z, a1.w};
        bf16x8 ahi, alo;
        split8(av, ahi, alo);
        #pragma unroll
        for (int nt = 0; nt < 8; ++nt) {
            bf16x8 bh = Bh[(kt * 8 + nt) * 64 + lane];
            bf16x8 bl = Bl[(kt * 8 + nt) * 64 + lane];
            acc[nt] = __builtin_amdgcn_mfma_f32_16x16x32_bf16(ahi, bl, acc[nt], 0, 0, 0);
            acc[nt] = __builtin_amdgcn_mfma_f32_16x16x32_bf16(alo, bh, acc[nt], 0, 0, 0);
            acc[nt] = __builtin_amdgcn_mfma_f32_16x16x32_bf16(ahi, bh, acc[nt], 0, 0, 0);
        }
    }

    #pragma unroll
    for (int nt = 0; nt < 8; ++nt) {
        float s = 0.f, q = 0.f;
        #pragma unroll
        for (int qq = 0; qq < 4; ++qq) {
            int node = nb + lg * 4 + qq;
            float v = acc[nt][qq];
            if (node < NN) {
                h[node * H2C + nt * 16 + lr] = v;
                s += v;
                q += v * v;
            }
        }
        ps[(nt * 16 + lr) * 16 + wave * 4 + lg] = s;
        pq[(nt * 16 + lr) * 16 + wave * 4 + lg] = q;
    }
    __syncthreads();
    if (t < 128) {
        float s = 0.f, q = 0.f;
        #pragma unroll
        for (int i = 0; i < 16; ++i) { s += ps[t * 16 + i]; q += pq[t * 16 + i]; }
        partials[blockIdx.x * 256 + t]       = s;
        partials[blockIdx.x * 256 + 128 + t] = q;
    }
}

// ---------------------------------------------------------------------------
// K4: reduce partials -> BN scale/bias (1024 threads, vectorized).
// ---------------------------------------------------------------------------
__global__ __launch_bounds__(1024) void k_bn_finalize(
    const float* __restrict__ partials, int nblk,
    const float* __restrict__ gamma, const float* __restrict__ beta,
    float* __restrict__ sb)
{
    const int t = threadIdx.x;
    const int f = t & 63;
    const int g = t >> 6;

    float4 acc = {0.f, 0.f, 0.f, 0.f};
    for (int b = g; b < nblk; b += 16) {
        float4 v = *(const float4*)&partials[b * 256 + f * 4];
        acc.x += v.x; acc.y += v.y; acc.z += v.z; acc.w += v.w;
    }

    __shared__ __align__(16) float4 red[16][64];
    red[g][f] = acc;
    __syncthreads();
    #pragma unroll
    for (int s = 8; s > 0; s >>= 1) {
        if (g < s) {
            float4 o = red[g + s][f];
            acc.x += o.x; acc.y += o.y; acc.z += o.z; acc.w += o.w;
            red[g][f] = acc;
        }
        __syncthreads();
    }

    if (t < 128) {
        const float* row = (const float*)&red[0][0];
        float s = row[t];
        float q = row[128 + t];
        float mean = s / (float)NN;
        float var  = q / (float)NN - mean * mean;
        float scale = gamma[t] * rsqrtf(var + 1e-5f);
        float bias  = beta[t] - mean * scale;
        sb[t]       = scale;
        sb[128 + t] = bias;
    }
}

// ---------------------------------------------------------------------------
// K5 (MFMA): out2 = relu(h*scale+bias) @ w2.T  [N,128]->[N,64]
// ---------------------------------------------------------------------------
__global__ __launch_bounds__(256) void k_lin3(
    const float* __restrict__ h, const short* __restrict__ p2hi,
    const short* __restrict__ p2lo, const float* __restrict__ sb,
    float* __restrict__ out)
{
    const int lane = threadIdx.x & 63, wave = threadIdx.x >> 6;
    const int lr = lane & 15, lg = lane >> 4;
    const int nb = blockIdx.x * 64 + wave * 16;
    const bf16x8* Bh = (const bf16x8*)p2hi;
    const bf16x8* Bl = (const bf16x8*)p2lo;
    int row = nb + lr; if (row > NN - 1) row = NN - 1;

    f32x4 acc[4];
    #pragma unroll
    for (int i = 0; i < 4; ++i) acc[i] = (f32x4){0.f, 0.f, 0.f, 0.f};

    #pragma unroll
    for (int kt = 0; kt < 4; ++kt) {
        const int k0 = kt * 32 + lg * 8;
        float4 sc0 = *(const float4*)&sb[k0],       sc1 = *(const float4*)&sb[k0 + 4];
        float4 bi0 = *(const float4*)&sb[128 + k0], bi1 = *(const float4*)&sb[128 + k0 + 4];
        const float* ap = h + (size_t)row * H2C + k0;
        float4 a0 = *(const float4*)ap, a1 = *(const float4*)(ap + 4);
        float av[8]  = {a0.x, a0.y, a0.z, a0.w, a1.x, a1.y, a1.z, a1.w};
        float scv[8] = {sc0.x, sc0.y, sc0.z, sc0.w, sc1.x, sc1.y, sc1.z, sc1.w};
        float biv[8] = {bi0.x, bi0.y, bi0.z, bi0.w, bi1.x, bi1.y, bi1.z, bi1.w};
        float rv[8];
        #pragma unroll
        for (int j = 0; j < 8; ++j) {
            float v = av[j] * scv[j] + biv[j];
            rv[j] = v > 0.f ? v : 0.f;
        }
        bf16x8 ahi, alo;
        split8(rv, ahi, alo);
        #pragma unroll
        for (int nt = 0; nt < 4; ++nt) {
            bf16x8 bh = Bh[(kt * 4 + nt) * 64 + lane];
            bf16x8 bl = Bl[(kt * 4 + nt) * 64 + lane];
            acc[nt] = __builtin_amdgcn_mfma_f32_16x16x32_bf16(ahi, bl, acc[nt], 0, 0, 0);
            acc[nt] = __builtin_amdgcn_mfma_f32_16x16x32_bf16(alo, bh, acc[nt], 0, 0, 0);
            acc[nt] = __builtin_amdgcn_mfma_f32_16x16x32_bf16(ahi, bh, acc[nt], 0, 0, 0);
        }
    }
    #pragma unroll
    for (int nt = 0; nt < 4; ++nt)
        #pragma unroll
        for (int q = 0; q < 4; ++q) {
            int node = nb + lg * 4 + q;
            if (node < NN) out[node * HC + nt * 16 + lr] = acc[nt][q];
        }
}

// ---------------------------------------------------------------------------
extern "C" void kernel_launch(void* const* d_in, const int* in_sizes, int n_in,
                              void* d_out, int out_size, void* d_ws, size_t ws_size,
                              hipStream_t stream) {
    const float* x         = (const float*)d_in[0];
    const float* edge_attr = (const float*)d_in[1];
    const float* w_src     = (const float*)d_in[2];
    const float* w_dst     = (const float*)d_in[3];
    const float* w_edge    = (const float*)d_in[4];
    const float* w1        = (const float*)d_in[5];
    const float* gamma     = (const float*)d_in[6];
    const float* beta      = (const float*)d_in[7];
    const float* w2        = (const float*)d_in[8];
    const int*   eidx      = (const int*)d_in[9];    // [2][E], row 0 = src
    const int*   nbr       = (const int*)d_in[10];   // [N][K]

    float* ws   = (float*)d_ws;
    float* srcP = ws;                    // N*64 (permuted)
    float* dstf = ws + 3200000;          // N*64
    float* outf = ws + 6400000;          // N*64
    float* h    = ws + 9600000;          // N*128
    float* part = ws + 16000000;         // NBLK*256
    float* sb   = ws + 16250000;         // 256
    short* sp   = (short*)(ws + 16300000);
    short* pAhi = sp;                    // 16384 shorts
    short* pAlo = sp + 16384;
    short* p1hi = sp + 32768;            // 8192
    short* p1lo = sp + 40960;
    short* p2hi = sp + 49152;            // 8192
    short* p2lo = sp + 57344;
    short* pE   = sp + 65536;            // 2048

    hipLaunchKernelGGL(k_prep,          dim3(32),    dim3(256),  0, stream,
                       w_src, w_dst, w1, w2, w_edge,
                       pAhi, pAlo, p1hi, p1lo, p2hi, p2lo, pE);
    hipLaunchKernelGGL(k_lin1,          dim3(NBLK),  dim3(256),  0, stream,
                       x, pAhi, pAlo, srcP, dstf);
    hipLaunchKernelGGL(k_edge_agg_mfma, dim3(6250),  dim3(256),  0, stream,
                       srcP, dstf, edge_attr, pE, eidx, nbr, outf);
    hipLaunchKernelGGL(k_lin2,          dim3(NBLK),  dim3(256),  0, stream,
                       outf, p1hi, p1lo, h, part);
    hipLaunchKernelGGL(k_bn_finalize,   dim3(1),     dim3(1024), 0, stream,
                       part, NBLK, gamma, beta, sb);
    hipLaunchKernelGGL(k_lin3,          dim3(NBLK),  dim3(256),  0, stream,
                       h, p2hi, p2lo, sb, (float*)d_out);
}

// Round 7
// 152.002 us; speedup vs baseline: 1.0234x; 1.0234x over previous
//
#include <hip/hip_runtime.h>
#include <hip/hip_bf16.h>
#include <float.h>

#define NN 50000
#define KNB 32
#define INC 128
#define HC 64
#define EDD 32
#define H2C 128
#define NBLK 782    // ceil(50000/64)
#define GRID2 1024
#define STRIDE2 (GRID2 * 4)   // waves in K2 grid

typedef __attribute__((ext_vector_type(8))) short bf16x8;
typedef __attribute__((ext_vector_type(4))) float f32x4;

__device__ __forceinline__ short f2bf(float f) {
    unsigned u = __builtin_bit_cast(unsigned, f);
    u += 0x7fffu + ((u >> 16) & 1u);          // RTNE
    return (short)(u >> 16);
}
__device__ __forceinline__ float bf2f(short h) {
    unsigned u = ((unsigned)(unsigned short)h) << 16;
    return __builtin_bit_cast(float, u);
}

// ---------------------------------------------------------------------------
// K0: pre-convert weights to fragment-ordered bf16 buffers.
// ---------------------------------------------------------------------------
__global__ __launch_bounds__(256) void k_prep(
    const float* __restrict__ w_src, const float* __restrict__ w_dst,
    const float* __restrict__ w1, const float* __restrict__ w2,
    const float* __restrict__ w_edge,
    short* __restrict__ pAhi, short* __restrict__ pAlo,
    short* __restrict__ p1hi, short* __restrict__ p1lo,
    short* __restrict__ p2hi, short* __restrict__ p2lo,
    short* __restrict__ pE)
{
    const int tid = blockIdx.x * 256 + threadIdx.x;
    const int nT  = gridDim.x * 256;
    for (int idx = tid; idx < 16384; idx += nT) {
        int kt = (idx >> 12) & 3, nt = (idx >> 9) & 7, lane = (idx >> 3) & 63, j = idx & 7;
        int lr = lane & 15, lg = lane >> 4;
        int ch = nt * 16 + lr, k = kt * 32 + lg * 8 + j;
        float f = (ch < 64) ? w_src[ch * 128 + k] : w_dst[(ch - 64) * 128 + k];
        short hi = f2bf(f);
        pAhi[idx] = hi; pAlo[idx] = f2bf(f - bf2f(hi));
    }
    for (int idx = tid; idx < 8192; idx += nT) {
        int kt = (idx >> 12) & 1, nt = (idx >> 9) & 7, lane = (idx >> 3) & 63, j = idx & 7;
        int lr = lane & 15, lg = lane >> 4;
        int ch = nt * 16 + lr, k = kt * 32 + lg * 8 + j;
        float f = w1[ch * 64 + k];
        short hi = f2bf(f);
        p1hi[idx] = hi; p1lo[idx] = f2bf(f - bf2f(hi));
    }
    for (int idx = tid; idx < 8192; idx += nT) {
        int kt = (idx >> 11) & 3, nt = (idx >> 9) & 3, lane = (idx >> 3) & 63, j = idx & 7;
        int lr = lane & 15, lg = lane >> 4;
        int ch = nt * 16 + lr, k = kt * 32 + lg * 8 + j;
        float f = w2[ch * 128 + k];
        short hi = f2bf(f);
        p2hi[idx] = hi; p2lo[idx] = f2bf(f - bf2f(hi));
    }
    for (int idx = tid; idx < 2048; idx += nT) {
        int nt = (idx >> 9) & 3, lane = (idx >> 3) & 63, j = idx & 7;
        int lr = lane & 15, lg = lane >> 4;
        int ch = nt * 16 + lr, k = lg * 8 + j;
        pE[idx] = f2bf(w_edge[ch * EDD + k]);
    }
}

__device__ __forceinline__ void split8(const float* av, bf16x8& ahi, bf16x8& alo) {
    #pragma unroll
    for (int j = 0; j < 8; ++j) {
        short h = f2bf(av[j]);
        ahi[j] = h;
        alo[j] = f2bf(av[j] - bf2f(h));
    }
}

// ---------------------------------------------------------------------------
// K1 (MFMA): [srcP|dstf] = x @ [w_src;w_dst].T ; srcP stored permuted:
// srcP[node*64 + lr*4 + nt] = src_ch[nt*16+lr]
// ---------------------------------------------------------------------------
__global__ __launch_bounds__(256) void k_lin1(
    const float* __restrict__ x, const short* __restrict__ pAhi,
    const short* __restrict__ pAlo, float* __restrict__ srcP,
    float* __restrict__ dstf)
{
    const int lane = threadIdx.x & 63, wave = threadIdx.x >> 6;
    const int lr = lane & 15, lg = lane >> 4;
    const int nb = blockIdx.x * 64 + wave * 16;
    const bf16x8* Bh = (const bf16x8*)pAhi;
    const bf16x8* Bl = (const bf16x8*)pAlo;
    int row = nb + lr; if (row > NN - 1) row = NN - 1;

    f32x4 acc[8];
    #pragma unroll
    for (int i = 0; i < 8; ++i) acc[i] = (f32x4){0.f, 0.f, 0.f, 0.f};

    #pragma unroll
    for (int kt = 0; kt < 4; ++kt) {
        const float* ap = x + (size_t)row * INC + kt * 32 + lg * 8;
        float4 a0 = *(const float4*)ap, a1 = *(const float4*)(ap + 4);
        float av[8] = {a0.x, a0.y, a0.z, a0.w, a1.x, a1.y, a1.z, a1.w};
        bf16x8 ahi, alo;
        split8(av, ahi, alo);
        #pragma unroll
        for (int nt = 0; nt < 8; ++nt) {
            bf16x8 bh = Bh[(kt * 8 + nt) * 64 + lane];
            bf16x8 bl = Bl[(kt * 8 + nt) * 64 + lane];
            acc[nt] = __builtin_amdgcn_mfma_f32_16x16x32_bf16(ahi, bl, acc[nt], 0, 0, 0);
            acc[nt] = __builtin_amdgcn_mfma_f32_16x16x32_bf16(alo, bh, acc[nt], 0, 0, 0);
            acc[nt] = __builtin_amdgcn_mfma_f32_16x16x32_bf16(ahi, bh, acc[nt], 0, 0, 0);
        }
    }
    #pragma unroll
    for (int nt = 0; nt < 8; ++nt)
        #pragma unroll
        for (int q = 0; q < 4; ++q) {
            int node = nb + lg * 4 + q;
            if (node < NN) {
                float v = acc[nt][q];
                if (nt < 4) srcP[node * HC + lr * 4 + nt] = v;     // permuted
                else        dstf[node * HC + (nt - 4) * 16 + lr] = v;
            }
        }
}

// ---------------------------------------------------------------------------
// K2 (MFMA, persistent + 2-stage software pipeline): one wave loops over
// nodes w, w+STRIDE2, ...; while computing node i, the gathers for node i+1
// and esrc for node i+2 are already in flight.
// ---------------------------------------------------------------------------
struct NodeState {
    f32x4 at[4];      // edge_attr fragments (raw f32)
    f32x4 xj0[4];     // gathered src features, mt=0
    f32x4 xj1[4];     // mt=1
    int4  e0, e1;     // esrc slots
    int   nbv;
    float d;
};

__device__ __forceinline__ void load_esrc(NodeState& s, const int* __restrict__ esrc,
                                          int node, int lg) {
    s.e0 = *(const int4*)&esrc[node * KNB + lg * 4];
    s.e1 = *(const int4*)&esrc[node * KNB + 16 + lg * 4];
}

__device__ __forceinline__ void issue_state(NodeState& s,
    const float* __restrict__ edge_attr, const int* __restrict__ nbr,
    const float* __restrict__ dstf, int node, int lane, int lr, int lg) {
    const f32x4* ab = (const f32x4*)(edge_attr + (size_t)node * KNB * EDD);
    #pragma unroll
    for (int mt = 0; mt < 2; ++mt) {
        int off = ((mt * 16 + lr) * EDD + lg * 8) >> 2;   // in f32x4 units
        s.at[mt * 2]     = __builtin_nontemporal_load(ab + off);
        s.at[mt * 2 + 1] = __builtin_nontemporal_load(ab + off + 1);
    }
    s.nbv = nbr[node * KNB + (lane & 31)];
    s.d   = dstf[node * HC + lane];
}

__device__ __forceinline__ void issue_gathers(NodeState& s,
    const float* __restrict__ srcP, int lr) {
    int i0[4] = {s.e0.x, s.e0.y, s.e0.z, s.e0.w};
    int i1[4] = {s.e1.x, s.e1.y, s.e1.z, s.e1.w};
    #pragma unroll
    for (int r = 0; r < 4; ++r)
        s.xj0[r] = *(const f32x4*)&srcP[(size_t)i0[r] * HC + lr * 4];
    #pragma unroll
    for (int r = 0; r < 4; ++r)
        s.xj1[r] = *(const f32x4*)&srcP[(size_t)i1[r] * HC + lr * 4];
}

__device__ __forceinline__ float node_compute(const NodeState& s, unsigned vmask,
                                              const bf16x8 bfrag[4], int lg) {
    // attr -> bf16 A-fragments
    bf16x8 afrag[2];
    #pragma unroll
    for (int mt = 0; mt < 2; ++mt) {
        #pragma unroll
        for (int j = 0; j < 8; ++j) {
            float v = (j < 4) ? s.at[mt * 2][j] : s.at[mt * 2 + 1][j - 4];
            afrag[mt][j] = f2bf(v);
        }
    }
    // projection
    f32x4 p[2][4];
    #pragma unroll
    for (int mt = 0; mt < 2; ++mt)
        #pragma unroll
        for (int nt = 0; nt < 4; ++nt) {
            f32x4 z = {0.f, 0.f, 0.f, 0.f};
            p[mt][nt] = __builtin_amdgcn_mfma_f32_16x16x32_bf16(
                afrag[mt], bfrag[nt], z, 0, 0, 0);
        }
    // validity only needed for edges 16..31 (deg >= 16 guaranteed)
    float vf[4];
    #pragma unroll
    for (int r = 0; r < 4; ++r)
        vf[r] = ((vmask >> (16 + lg * 4 + r)) & 1u) ? 1.f : 0.f;

    // softmax-weighted mean, no max-subtract, eps folded out (added by caller)
    float res[4];
    #pragma unroll
    for (int nt = 0; nt < 4; ++nt) {
        float se = 0.f, ws = 0.f;
        #pragma unroll
        for (int r = 0; r < 4; ++r) {
            float m = fmaxf(p[0][nt][r] + s.xj0[r][nt], 0.f);
            float t = __expf(m);
            se += t;
            ws = fmaf(m, t, ws);
        }
        #pragma unroll
        for (int r = 0; r < 4; ++r) {
            float m = fmaxf(p[1][nt][r] + s.xj1[r][nt], 0.f);
            float t = __expf(m) * vf[r];
            se += t;
            ws = fmaf(m, t, ws);
        }
        se += __shfl_xor(se, 16, 64); ws += __shfl_xor(ws, 16, 64);
        se += __shfl_xor(se, 32, 64); ws += __shfl_xor(ws, 32, 64);
        res[nt] = ws / (se + 1e-16f);
    }
    float r01 = (lg & 1) ? res[1] : res[0];
    float r23 = (lg & 1) ? res[3] : res[2];
    return (lg & 2) ? r23 : r01;
}

__global__ __launch_bounds__(256) void k_edge_agg_mfma(
    const float* __restrict__ srcP, const float* __restrict__ dstf,
    const float* __restrict__ edge_attr, const short* __restrict__ pE,
    const int* __restrict__ esrc, const int* __restrict__ nbr,
    float* __restrict__ outf)
{
    const int lane = threadIdx.x & 63;
    const int wv   = threadIdx.x >> 6;
    const int w    = blockIdx.x * 4 + wv;
    const int lr = lane & 15, lg = lane >> 4;

    const bf16x8* Bp = (const bf16x8*)pE;
    bf16x8 bfrag[4];
    #pragma unroll
    for (int nt = 0; nt < 4; ++nt) bfrag[nt] = Bp[nt * 64 + lane];

    NodeState A, B;
    int n = w;
    // prologue: full state for n, esrc for n+STRIDE2
    load_esrc(A, esrc, n, lg);
    issue_state(A, edge_attr, nbr, dstf, n, lane, lr, lg);
    issue_gathers(A, srcP, lr);
    load_esrc(B, esrc, min(n + STRIDE2, NN - 1), lg);

    for (;;) {
        {   // BODY: compute A, prefetch B(gathers+state), A.esrc <- n+2S
            int nn = min(n + STRIDE2, NN - 1);
            issue_gathers(B, srcP, lr);
            issue_state(B, edge_attr, nbr, dstf, nn, lane, lr, lg);
            load_esrc(A, esrc, min(n + 2 * STRIDE2, NN - 1), lg);
            unsigned vm = (unsigned)__ballot((lane < 32) && (A.nbv >= 0));
            float rr = node_compute(A, vm, bfrag, lg);
            outf[n * HC + lane] = rr + A.d + 1e-7f;
            n += STRIDE2; if (n >= NN) break;
        }
        {   // BODY: compute B, prefetch A, B.esrc <- n+2S
            int nn = min(n + STRIDE2, NN - 1);
            issue_gathers(A, srcP, lr);
            issue_state(A, edge_attr, nbr, dstf, nn, lane, lr, lg);
            load_esrc(B, esrc, min(n + 2 * STRIDE2, NN - 1), lg);
            unsigned vm = (unsigned)__ballot((lane < 32) && (B.nbv >= 0));
            float rr = node_compute(B, vm, bfrag, lg);
            outf[n * HC + lane] = rr + B.d + 1e-7f;
            n += STRIDE2; if (n >= NN) break;
        }
    }
}

// ---------------------------------------------------------------------------
// K3 (MFMA): h = out @ w1.T  [N,64]->[N,128]  + per-block BN partials.
// ---------------------------------------------------------------------------
__global__ __launch_bounds__(256) void k_lin2(
    const float* __restrict__ outf, const short* __restrict__ p1hi,
    const short* __restrict__ p1lo, float* __restrict__ h,
    float* __restrict__ partials)
{
    __shared__ float ps[128 * 16], pq[128 * 16];
    const int t = threadIdx.x;
    const int lane = t & 63, wave = t >> 6;
    const int lr = lane & 15, lg = lane >> 4;
    const int nb = blockIdx.x * 64 + wave * 16;
    const bf16x8* Bh = (const bf16x8*)p1hi;
    const bf16x8* Bl = (const bf16x8*)p1lo;
    int row = nb + lr; if (row > NN - 1) row = NN - 1;

    f32x4 acc[8];
    #pragma unroll
    for (int i = 0; i < 8; ++i) acc[i] = (f32x4){0.f, 0.f, 0.f, 0.f};

    #pragma unroll
    for (int kt = 0; kt < 2; ++kt) {
        const float* ap = outf + (size_t)row * HC + kt * 32 + lg * 8;
        float4 a0 = *(const float4*)ap, a1 = *(const float4*)(ap + 4);
        float av[8] = {a0.x, a0.y, a0.z, a0.w, a1.x, a1.y, a1.z, a1.w};
        bf16x8 ahi, alo;
        split8(av, ahi, alo);
        #pragma unroll
        for (int nt = 0; nt < 8; ++nt) {
            bf16x8 bh = Bh[(kt * 8 + nt) * 64 + lane];
            bf16x8 bl = Bl[(kt * 8 + nt) * 64 + lane];
            acc[nt] = __builtin_amdgcn_mfma_f32_16x16x32_bf16(ahi, bl, acc[nt], 0, 0, 0);
            acc[nt] = __builtin_amdgcn_mfma_f32_16x16x32_bf16(alo, bh, acc[nt], 0, 0, 0);
            acc[nt] = __builtin_amdgcn_mfma_f32_16x16x32_bf16(ahi, bh, acc[nt], 0, 0, 0);
        }
    }

    #pragma unroll
    for (int nt = 0; nt < 8; ++nt) {
        float s = 0.f, q = 0.f;
        #pragma unroll
        for (int qq = 0; qq < 4; ++qq) {
            int node = nb + lg * 4 + qq;
            float v = acc[nt][qq];
            if (node < NN) {
                h[node * H2C + nt * 16 + lr] = v;
                s += v;
                q += v * v;
            }
        }
        ps[(nt * 16 + lr) * 16 + wave * 4 + lg] = s;
        pq[(nt * 16 + lr) * 16 + wave * 4 + lg] = q;
    }
    __syncthreads();
    if (t < 128) {
        float s = 0.f, q = 0.f;
        #pragma unroll
        for (int i = 0; i < 16; ++i) { s += ps[t * 16 + i]; q += pq[t * 16 + i]; }
        partials[blockIdx.x * 256 + t]       = s;
        partials[blockIdx.x * 256 + 128 + t] = q;
    }
}

// ---------------------------------------------------------------------------
// K4: reduce partials -> BN scale/bias (1024 threads, vectorized).
// ---------------------------------------------------------------------------
__global__ __launch_bounds__(1024) void k_bn_finalize(
    const float* __restrict__ partials, int nblk,
    const float* __restrict__ gamma, const float* __restrict__ beta,
    float* __restrict__ sb)
{
    const int t = threadIdx.x;
    const int f = t & 63;
    const int g = t >> 6;

    float4 acc = {0.f, 0.f, 0.f, 0.f};
    for (int b = g; b < nblk; b += 16) {
        float4 v = *(const float4*)&partials[b * 256 + f * 4];
        acc.x += v.x; acc.y += v.y; acc.z += v.z; acc.w += v.w;
    }

    __shared__ __align__(16) float4 red[16][64];
    red[g][f] = acc;
    __syncthreads();
    #pragma unroll
    for (int s = 8; s > 0; s >>= 1) {
        if (g < s) {
            float4 o = red[g + s][f];
            acc.x += o.x; acc.y += o.y; acc.z += o.z; acc.w += o.w;
            red[g][f] = acc;
        }
        __syncthreads();
    }

    if (t < 128) {
        const float* row = (const float*)&red[0][0];
        float s = row[t];
        float q = row[128 + t];
        float mean = s / (float)NN;
        float var  = q / (float)NN - mean * mean;
        float scale = gamma[t] * rsqrtf(var + 1e-5f);
        float bias  = beta[t] - mean * scale;
        sb[t]       = scale;
        sb[128 + t] = bias;
    }
}

// ---------------------------------------------------------------------------
// K5 (MFMA): out2 = relu(h*scale+bias) @ w2.T  [N,128]->[N,64]
// ---------------------------------------------------------------------------
__global__ __launch_bounds__(256) void k_lin3(
    const float* __restrict__ h, const short* __restrict__ p2hi,
    const short* __restrict__ p2lo, const float* __restrict__ sb,
    float* __restrict__ out)
{
    const int lane = threadIdx.x & 63, wave = threadIdx.x >> 6;
    const int lr = lane & 15, lg = lane >> 4;
    const int nb = blockIdx.x * 64 + wave * 16;
    const bf16x8* Bh = (const bf16x8*)p2hi;
    const bf16x8* Bl = (const bf16x8*)p2lo;
    int row = nb + lr; if (row > NN - 1) row = NN - 1;

    f32x4 acc[4];
    #pragma unroll
    for (int i = 0; i < 4; ++i) acc[i] = (f32x4){0.f, 0.f, 0.f, 0.f};

    #pragma unroll
    for (int kt = 0; kt < 4; ++kt) {
        const int k0 = kt * 32 + lg * 8;
        float4 sc0 = *(const float4*)&sb[k0],       sc1 = *(const float4*)&sb[k0 + 4];
        float4 bi0 = *(const float4*)&sb[128 + k0], bi1 = *(const float4*)&sb[128 + k0 + 4];
        const float* ap = h + (size_t)row * H2C + k0;
        float4 a0 = *(const float4*)ap, a1 = *(const float4*)(ap + 4);
        float av[8]  = {a0.x, a0.y, a0.z, a0.w, a1.x, a1.y, a1.z, a1.w};
        float scv[8] = {sc0.x, sc0.y, sc0.z, sc0.w, sc1.x, sc1.y, sc1.z, sc1.w};
        float biv[8] = {bi0.x, bi0.y, bi0.z, bi0.w, bi1.x, bi1.y, bi1.z, bi1.w};
        float rv[8];
        #pragma unroll
        for (int j = 0; j < 8; ++j) {
            float v = av[j] * scv[j] + biv[j];
            rv[j] = v > 0.f ? v : 0.f;
        }
        bf16x8 ahi, alo;
        split8(rv, ahi, alo);
        #pragma unroll
        for (int nt = 0; nt < 4; ++nt) {
            bf16x8 bh = Bh[(kt * 4 + nt) * 64 + lane];
            bf16x8 bl = Bl[(kt * 4 + nt) * 64 + lane];
            acc[nt] = __builtin_amdgcn_mfma_f32_16x16x32_bf16(ahi, bl, acc[nt], 0, 0, 0);
            acc[nt] = __builtin_amdgcn_mfma_f32_16x16x32_bf16(alo, bh, acc[nt], 0, 0, 0);
            acc[nt] = __builtin_amdgcn_mfma_f32_16x16x32_bf16(ahi, bh, acc[nt], 0, 0, 0);
        }
    }
    #pragma unroll
    for (int nt = 0; nt < 4; ++nt)
        #pragma unroll
        for (int q = 0; q < 4; ++q) {
            int node = nb + lg * 4 + q;
            if (node < NN) out[node * HC + nt * 16 + lr] = acc[nt][q];
        }
}

// ---------------------------------------------------------------------------
extern "C" void kernel_launch(void* const* d_in, const int* in_sizes, int n_in,
                              void* d_out, int out_size, void* d_ws, size_t ws_size,
                              hipStream_t stream) {
    const float* x         = (const float*)d_in[0];
    const float* edge_attr = (const float*)d_in[1];
    const float* w_src     = (const float*)d_in[2];
    const float* w_dst     = (const float*)d_in[3];
    const float* w_edge    = (const float*)d_in[4];
    const float* w1        = (const float*)d_in[5];
    const float* gamma     = (const float*)d_in[6];
    const float* beta      = (const float*)d_in[7];
    const float* w2        = (const float*)d_in[8];
    const int*   eidx      = (const int*)d_in[9];    // [2][E], row 0 = src
    const int*   nbr       = (const int*)d_in[10];   // [N][K]

    float* ws   = (float*)d_ws;
    float* srcP = ws;                    // N*64 (permuted)
    float* dstf = ws + 3200000;          // N*64
    float* outf = ws + 6400000;          // N*64
    float* h    = ws + 9600000;          // N*128
    float* part = ws + 16000000;         // NBLK*256
    float* sb   = ws + 16250000;         // 256
    short* sp   = (short*)(ws + 16300000);
    short* pAhi = sp;                    // 16384 shorts
    short* pAlo = sp + 16384;
    short* p1hi = sp + 32768;            // 8192
    short* p1lo = sp + 40960;
    short* p2hi = sp + 49152;            // 8192
    short* p2lo = sp + 57344;
    short* pE   = sp + 65536;            // 2048

    hipLaunchKernelGGL(k_prep,          dim3(32),    dim3(256),  0, stream,
                       w_src, w_dst, w1, w2, w_edge,
                       pAhi, pAlo, p1hi, p1lo, p2hi, p2lo, pE);
    hipLaunchKernelGGL(k_lin1,          dim3(NBLK),  dim3(256),  0, stream,
                       x, pAhi, pAlo, srcP, dstf);
    hipLaunchKernelGGL(k_edge_agg_mfma, dim3(GRID2), dim3(256),  0, stream,
                       srcP, dstf, edge_attr, pE, eidx, nbr, outf);
    hipLaunchKernelGGL(k_lin2,          dim3(NBLK),  dim3(256),  0, stream,
                       outf, p1hi, p1lo, h, part);
    hipLaunchKernelGGL(k_bn_finalize,   dim3(1),     dim3(1024), 0, stream,
                       part, NBLK, gamma, beta, sb);
    hipLaunchKernelGGL(k_lin3,          dim3(NBLK),  dim3(256),  0, stream,
                       h, p2hi, p2lo, sb, (float*)d_out);
}

// Round 8
// 141.594 us; speedup vs baseline: 1.0987x; 1.0735x over previous
//
#include <hip/hip_runtime.h>
#include <hip/hip_bf16.h>
#include <float.h>

#define NN 50000
#define KNB 32
#define INC 128
#define HC 64
#define EDD 32
#define H2C 128
#define NBLK 782    // ceil(50000/64)
#define GRID2 2048
#define STRIDE2 (GRID2 * 4)   // waves in K2 grid

typedef __attribute__((ext_vector_type(8))) short bf16x8;
typedef __attribute__((ext_vector_type(4))) float f32x4;
typedef __attribute__((ext_vector_type(4))) _Float16 f16x4;

__device__ __forceinline__ short f2bf(float f) {
    unsigned u = __builtin_bit_cast(unsigned, f);
    u += 0x7fffu + ((u >> 16) & 1u);          // RTNE
    return (short)(u >> 16);
}
__device__ __forceinline__ float bf2f(short h) {
    unsigned u = ((unsigned)(unsigned short)h) << 16;
    return __builtin_bit_cast(float, u);
}

// ---------------------------------------------------------------------------
// K0: pre-convert weights to fragment-ordered bf16 buffers.
// ---------------------------------------------------------------------------
__global__ __launch_bounds__(256) void k_prep(
    const float* __restrict__ w_src, const float* __restrict__ w_dst,
    const float* __restrict__ w1, const float* __restrict__ w2,
    const float* __restrict__ w_edge,
    short* __restrict__ pAhi, short* __restrict__ pAlo,
    short* __restrict__ p1hi, short* __restrict__ p1lo,
    short* __restrict__ p2hi, short* __restrict__ p2lo,
    short* __restrict__ pE)
{
    const int tid = blockIdx.x * 256 + threadIdx.x;
    const int nT  = gridDim.x * 256;
    for (int idx = tid; idx < 16384; idx += nT) {
        int kt = (idx >> 12) & 3, nt = (idx >> 9) & 7, lane = (idx >> 3) & 63, j = idx & 7;
        int lr = lane & 15, lg = lane >> 4;
        int ch = nt * 16 + lr, k = kt * 32 + lg * 8 + j;
        float f = (ch < 64) ? w_src[ch * 128 + k] : w_dst[(ch - 64) * 128 + k];
        short hi = f2bf(f);
        pAhi[idx] = hi; pAlo[idx] = f2bf(f - bf2f(hi));
    }
    for (int idx = tid; idx < 8192; idx += nT) {
        int kt = (idx >> 12) & 1, nt = (idx >> 9) & 7, lane = (idx >> 3) & 63, j = idx & 7;
        int lr = lane & 15, lg = lane >> 4;
        int ch = nt * 16 + lr, k = kt * 32 + lg * 8 + j;
        float f = w1[ch * 64 + k];
        short hi = f2bf(f);
        p1hi[idx] = hi; p1lo[idx] = f2bf(f - bf2f(hi));
    }
    for (int idx = tid; idx < 8192; idx += nT) {
        int kt = (idx >> 11) & 3, nt = (idx >> 9) & 3, lane = (idx >> 3) & 63, j = idx & 7;
        int lr = lane & 15, lg = lane >> 4;
        int ch = nt * 16 + lr, k = kt * 32 + lg * 8 + j;
        float f = w2[ch * 128 + k];
        short hi = f2bf(f);
        p2hi[idx] = hi; p2lo[idx] = f2bf(f - bf2f(hi));
    }
    for (int idx = tid; idx < 2048; idx += nT) {
        int nt = (idx >> 9) & 3, lane = (idx >> 3) & 63, j = idx & 7;
        int lr = lane & 15, lg = lane >> 4;
        int ch = nt * 16 + lr, k = lg * 8 + j;
        pE[idx] = f2bf(w_edge[ch * EDD + k]);
    }
}

__device__ __forceinline__ void split8(const float* av, bf16x8& ahi, bf16x8& alo) {
    #pragma unroll
    for (int j = 0; j < 8; ++j) {
        short h = f2bf(av[j]);
        ahi[j] = h;
        alo[j] = f2bf(av[j] - bf2f(h));
    }
}

// ---------------------------------------------------------------------------
// K1 (MFMA): [srcPh|dstf] = x @ [w_src;w_dst].T ; srcPh stored PERMUTED fp16:
// srcPh[node*64 + lr*4 + nt] = src_ch[nt*16+lr]  (row = 128B)
// ---------------------------------------------------------------------------
__global__ __launch_bounds__(256) void k_lin1(
    const float* __restrict__ x, const short* __restrict__ pAhi,
    const short* __restrict__ pAlo, _Float16* __restrict__ srcPh,
    float* __restrict__ dstf)
{
    const int lane = threadIdx.x & 63, wave = threadIdx.x >> 6;
    const int lr = lane & 15, lg = lane >> 4;
    const int nb = blockIdx.x * 64 + wave * 16;
    const bf16x8* Bh = (const bf16x8*)pAhi;
    const bf16x8* Bl = (const bf16x8*)pAlo;
    int row = nb + lr; if (row > NN - 1) row = NN - 1;

    f32x4 acc[8];
    #pragma unroll
    for (int i = 0; i < 8; ++i) acc[i] = (f32x4){0.f, 0.f, 0.f, 0.f};

    #pragma unroll
    for (int kt = 0; kt < 4; ++kt) {
        const float* ap = x + (size_t)row * INC + kt * 32 + lg * 8;
        float4 a0 = *(const float4*)ap, a1 = *(const float4*)(ap + 4);
        float av[8] = {a0.x, a0.y, a0.z, a0.w, a1.x, a1.y, a1.z, a1.w};
        bf16x8 ahi, alo;
        split8(av, ahi, alo);
        #pragma unroll
        for (int nt = 0; nt < 8; ++nt) {
            bf16x8 bh = Bh[(kt * 8 + nt) * 64 + lane];
            bf16x8 bl = Bl[(kt * 8 + nt) * 64 + lane];
            acc[nt] = __builtin_amdgcn_mfma_f32_16x16x32_bf16(ahi, bl, acc[nt], 0, 0, 0);
            acc[nt] = __builtin_amdgcn_mfma_f32_16x16x32_bf16(alo, bh, acc[nt], 0, 0, 0);
            acc[nt] = __builtin_amdgcn_mfma_f32_16x16x32_bf16(ahi, bh, acc[nt], 0, 0, 0);
        }
    }
    #pragma unroll
    for (int nt = 0; nt < 8; ++nt)
        #pragma unroll
        for (int q = 0; q < 4; ++q) {
            int node = nb + lg * 4 + q;
            if (node < NN) {
                float v = acc[nt][q];
                if (nt < 4) srcPh[node * HC + lr * 4 + nt] = (_Float16)v;  // permuted fp16
                else        dstf[node * HC + (nt - 4) * 16 + lr] = v;
            }
        }
}

// ---------------------------------------------------------------------------
// K2 (MFMA, persistent + 2-stage software pipeline, fp16 gathers).
// ---------------------------------------------------------------------------
struct NodeState {
    f32x4 at[4];      // edge_attr fragments (raw f32)
    f16x4 xj0[4];     // gathered src features (fp16), mt=0
    f16x4 xj1[4];     // mt=1
    int4  e0, e1;     // esrc slots
    int   nbv;
    float d;
};

__device__ __forceinline__ void load_esrc(NodeState& s, const int* __restrict__ esrc,
                                          int node, int lg) {
    s.e0 = *(const int4*)&esrc[node * KNB + lg * 4];
    s.e1 = *(const int4*)&esrc[node * KNB + 16 + lg * 4];
}

__device__ __forceinline__ void issue_state(NodeState& s,
    const float* __restrict__ edge_attr, const int* __restrict__ nbr,
    const float* __restrict__ dstf, int node, int lane, int lr, int lg) {
    const f32x4* ab = (const f32x4*)(edge_attr + (size_t)node * KNB * EDD);
    #pragma unroll
    for (int mt = 0; mt < 2; ++mt) {
        int off = ((mt * 16 + lr) * EDD + lg * 8) >> 2;   // in f32x4 units
        s.at[mt * 2]     = __builtin_nontemporal_load(ab + off);
        s.at[mt * 2 + 1] = __builtin_nontemporal_load(ab + off + 1);
    }
    s.nbv = nbr[node * KNB + (lane & 31)];
    s.d   = dstf[node * HC + lane];
}

__device__ __forceinline__ void issue_gathers(NodeState& s,
    const _Float16* __restrict__ srcPh, int lr) {
    int i0[4] = {s.e0.x, s.e0.y, s.e0.z, s.e0.w};
    int i1[4] = {s.e1.x, s.e1.y, s.e1.z, s.e1.w};
    #pragma unroll
    for (int r = 0; r < 4; ++r)
        s.xj0[r] = *(const f16x4*)&srcPh[(size_t)i0[r] * HC + lr * 4];
    #pragma unroll
    for (int r = 0; r < 4; ++r)
        s.xj1[r] = *(const f16x4*)&srcPh[(size_t)i1[r] * HC + lr * 4];
}

__device__ __forceinline__ float node_compute(const NodeState& s, unsigned vmask,
                                              const bf16x8 bfrag[4], int lg) {
    // attr -> bf16 A-fragments
    bf16x8 afrag[2];
    #pragma unroll
    for (int mt = 0; mt < 2; ++mt) {
        #pragma unroll
        for (int j = 0; j < 8; ++j) {
            float v = (j < 4) ? s.at[mt * 2][j] : s.at[mt * 2 + 1][j - 4];
            afrag[mt][j] = f2bf(v);
        }
    }
    // projection
    f32x4 p[2][4];
    #pragma unroll
    for (int mt = 0; mt < 2; ++mt)
        #pragma unroll
        for (int nt = 0; nt < 4; ++nt) {
            f32x4 z = {0.f, 0.f, 0.f, 0.f};
            p[mt][nt] = __builtin_amdgcn_mfma_f32_16x16x32_bf16(
                afrag[mt], bfrag[nt], z, 0, 0, 0);
        }
    // validity only needed for edges 16..31 (deg >= 16 guaranteed)
    float vf[4];
    #pragma unroll
    for (int r = 0; r < 4; ++r)
        vf[r] = ((vmask >> (16 + lg * 4 + r)) & 1u) ? 1.f : 0.f;

    // softmax-weighted mean, no max-subtract, eps folded out (added by caller)
    float res[4];
    #pragma unroll
    for (int nt = 0; nt < 4; ++nt) {
        float se = 0.f, ws = 0.f;
        #pragma unroll
        for (int r = 0; r < 4; ++r) {
            float m = fmaxf(p[0][nt][r] + (float)s.xj0[r][nt], 0.f);
            float t = __expf(m);
            se += t;
            ws = fmaf(m, t, ws);
        }
        #pragma unroll
        for (int r = 0; r < 4; ++r) {
            float m = fmaxf(p[1][nt][r] + (float)s.xj1[r][nt], 0.f);
            float t = __expf(m) * vf[r];
            se += t;
            ws = fmaf(m, t, ws);
        }
        se += __shfl_xor(se, 16, 64); ws += __shfl_xor(ws, 16, 64);
        se += __shfl_xor(se, 32, 64); ws += __shfl_xor(ws, 32, 64);
        res[nt] = ws / (se + 1e-16f);
    }
    float r01 = (lg & 1) ? res[1] : res[0];
    float r23 = (lg & 1) ? res[3] : res[2];
    return (lg & 2) ? r23 : r01;
}

__global__ __launch_bounds__(256) void k_edge_agg_mfma(
    const _Float16* __restrict__ srcPh, const float* __restrict__ dstf,
    const float* __restrict__ edge_attr, const short* __restrict__ pE,
    const int* __restrict__ esrc, const int* __restrict__ nbr,
    float* __restrict__ outf)
{
    const int lane = threadIdx.x & 63;
    const int wv   = threadIdx.x >> 6;
    const int w    = blockIdx.x * 4 + wv;
    const int lr = lane & 15, lg = lane >> 4;

    const bf16x8* Bp = (const bf16x8*)pE;
    bf16x8 bfrag[4];
    #pragma unroll
    for (int nt = 0; nt < 4; ++nt) bfrag[nt] = Bp[nt * 64 + lane];

    NodeState A, B;
    int n = w;
    if (n >= NN) return;
    // prologue: full state for n, esrc for n+STRIDE2
    load_esrc(A, esrc, n, lg);
    issue_state(A, edge_attr, nbr, dstf, n, lane, lr, lg);
    issue_gathers(A, srcPh, lr);
    load_esrc(B, esrc, min(n + STRIDE2, NN - 1), lg);

    for (;;) {
        {   // BODY: compute A, prefetch B(gathers+state), A.esrc <- n+2S
            int nn = min(n + STRIDE2, NN - 1);
            issue_gathers(B, srcPh, lr);
            issue_state(B, edge_attr, nbr, dstf, nn, lane, lr, lg);
            load_esrc(A, esrc, min(n + 2 * STRIDE2, NN - 1), lg);
            unsigned vm = (unsigned)__ballot((lane < 32) && (A.nbv >= 0));
            float rr = node_compute(A, vm, bfrag, lg);
            outf[n * HC + lane] = rr + A.d + 1e-7f;
            n += STRIDE2; if (n >= NN) break;
        }
        {   // BODY: compute B, prefetch A, B.esrc <- n+2S
            int nn = min(n + STRIDE2, NN - 1);
            issue_gathers(A, srcPh, lr);
            issue_state(A, edge_attr, nbr, dstf, nn, lane, lr, lg);
            load_esrc(B, esrc, min(n + 2 * STRIDE2, NN - 1), lg);
            unsigned vm = (unsigned)__ballot((lane < 32) && (B.nbv >= 0));
            float rr = node_compute(B, vm, bfrag, lg);
            outf[n * HC + lane] = rr + B.d + 1e-7f;
            n += STRIDE2; if (n >= NN) break;
        }
    }
}

// ---------------------------------------------------------------------------
// K3 (MFMA): h = out @ w1.T  [N,64]->[N,128]  + per-block BN partials.
// ---------------------------------------------------------------------------
__global__ __launch_bounds__(256) void k_lin2(
    const float* __restrict__ outf, const short* __restrict__ p1hi,
    const short* __restrict__ p1lo, float* __restrict__ h,
    float* __restrict__ partials)
{
    __shared__ float ps[128 * 16], pq[128 * 16];
    const int t = threadIdx.x;
    const int lane = t & 63, wave = t >> 6;
    const int lr = lane & 15, lg = lane >> 4;
    const int nb = blockIdx.x * 64 + wave * 16;
    const bf16x8* Bh = (const bf16x8*)p1hi;
    const bf16x8* Bl = (const bf16x8*)p1lo;
    int row = nb + lr; if (row > NN - 1) row = NN - 1;

    f32x4 acc[8];
    #pragma unroll
    for (int i = 0; i < 8; ++i) acc[i] = (f32x4){0.f, 0.f, 0.f, 0.f};

    #pragma unroll
    for (int kt = 0; kt < 2; ++kt) {
        const float* ap = outf + (size_t)row * HC + kt * 32 + lg * 8;
        float4 a0 = *(const float4*)ap, a1 = *(const float4*)(ap + 4);
        float av[8] = {a0.x, a0.y, a0.z, a0.w, a1.x, a1.y, a1.z, a1.w};
        bf16x8 ahi, alo;
        split8(av, ahi, alo);
        #pragma unroll
        for (int nt = 0; nt < 8; ++nt) {
            bf16x8 bh = Bh[(kt * 8 + nt) * 64 + lane];
            bf16x8 bl = Bl[(kt * 8 + nt) * 64 + lane];
            acc[nt] = __builtin_amdgcn_mfma_f32_16x16x32_bf16(ahi, bl, acc[nt], 0, 0, 0);
            acc[nt] = __builtin_amdgcn_mfma_f32_16x16x32_bf16(alo, bh, acc[nt], 0, 0, 0);
            acc[nt] = __builtin_amdgcn_mfma_f32_16x16x32_bf16(ahi, bh, acc[nt], 0, 0, 0);
        }
    }

    #pragma unroll
    for (int nt = 0; nt < 8; ++nt) {
        float s = 0.f, q = 0.f;
        #pragma unroll
        for (int qq = 0; qq < 4; ++qq) {
            int node = nb + lg * 4 + qq;
            float v = acc[nt][qq];
            if (node < NN) {
                h[node * H2C + nt * 16 + lr] = v;
                s += v;
                q += v * v;
            }
        }
        ps[(nt * 16 + lr) * 16 + wave * 4 + lg] = s;
        pq[(nt * 16 + lr) * 16 + wave * 4 + lg] = q;
    }
    __syncthreads();
    if (t < 128) {
        float s = 0.f, q = 0.f;
        #pragma unroll
        for (int i = 0; i < 16; ++i) { s += ps[t * 16 + i]; q += pq[t * 16 + i]; }
        partials[blockIdx.x * 256 + t]       = s;
        partials[blockIdx.x * 256 + 128 + t] = q;
    }
}

// ---------------------------------------------------------------------------
// K4: reduce partials -> BN scale/bias (1024 threads, vectorized).
// ---------------------------------------------------------------------------
__global__ __launch_bounds__(1024) void k_bn_finalize(
    const float* __restrict__ partials, int nblk,
    const float* __restrict__ gamma, const float* __restrict__ beta,
    float* __restrict__ sb)
{
    const int t = threadIdx.x;
    const int f = t & 63;
    const int g = t >> 6;

    float4 acc = {0.f, 0.f, 0.f, 0.f};
    for (int b = g; b < nblk; b += 16) {
        float4 v = *(const float4*)&partials[b * 256 + f * 4];
        acc.x += v.x; acc.y += v.y; acc.z += v.z; acc.w += v.w;
    }

    __shared__ __align__(16) float4 red[16][64];
    red[g][f] = acc;
    __syncthreads();
    #pragma unroll
    for (int s = 8; s > 0; s >>= 1) {
        if (g < s) {
            float4 o = red[g + s][f];
            acc.x += o.x; acc.y += o.y; acc.z += o.z; acc.w += o.w;
            red[g][f] = acc;
        }
        __syncthreads();
    }

    if (t < 128) {
        const float* row = (const float*)&red[0][0];
        float s = row[t];
        float q = row[128 + t];
        float mean = s / (float)NN;
        float var  = q / (float)NN - mean * mean;
        float scale = gamma[t] * rsqrtf(var + 1e-5f);
        float bias  = beta[t] - mean * scale;
        sb[t]       = scale;
        sb[128 + t] = bias;
    }
}

// ---------------------------------------------------------------------------
// K5 (MFMA): out2 = relu(h*scale+bias) @ w2.T  [N,128]->[N,64]
// ---------------------------------------------------------------------------
__global__ __launch_bounds__(256) void k_lin3(
    const float* __restrict__ h, const short* __restrict__ p2hi,
    const short* __restrict__ p2lo, const float* __restrict__ sb,
    float* __restrict__ out)
{
    const int lane = threadIdx.x & 63, wave = threadIdx.x >> 6;
    const int lr = lane & 15, lg = lane >> 4;
    const int nb = blockIdx.x * 64 + wave * 16;
    const bf16x8* Bh = (const bf16x8*)p2hi;
    const bf16x8* Bl = (const bf16x8*)p2lo;
    int row = nb + lr; if (row > NN - 1) row = NN - 1;

    f32x4 acc[4];
    #pragma unroll
    for (int i = 0; i < 4; ++i) acc[i] = (f32x4){0.f, 0.f, 0.f, 0.f};

    #pragma unroll
    for (int kt = 0; kt < 4; ++kt) {
        const int k0 = kt * 32 + lg * 8;
        float4 sc0 = *(const float4*)&sb[k0],       sc1 = *(const float4*)&sb[k0 + 4];
        float4 bi0 = *(const float4*)&sb[128 + k0], bi1 = *(const float4*)&sb[128 + k0 + 4];
        const float* ap = h + (size_t)row * H2C + k0;
        float4 a0 = *(const float4*)ap, a1 = *(const float4*)(ap + 4);
        float av[8]  = {a0.x, a0.y, a0.z, a0.w, a1.x, a1.y, a1.z, a1.w};
        float scv[8] = {sc0.x, sc0.y, sc0.z, sc0.w, sc1.x, sc1.y, sc1.z, sc1.w};
        float biv[8] = {bi0.x, bi0.y, bi0.z, bi0.w, bi1.x, bi1.y, bi1.z, bi1.w};
        float rv[8];
        #pragma unroll
        for (int j = 0; j < 8; ++j) {
            float v = av[j] * scv[j] + biv[j];
            rv[j] = v > 0.f ? v : 0.f;
        }
        bf16x8 ahi, alo;
        split8(rv, ahi, alo);
        #pragma unroll
        for (int nt = 0; nt < 4; ++nt) {
            bf16x8 bh = Bh[(kt * 4 + nt) * 64 + lane];
            bf16x8 bl = Bl[(kt * 4 + nt) * 64 + lane];
            acc[nt] = __builtin_amdgcn_mfma_f32_16x16x32_bf16(ahi, bl, acc[nt], 0, 0, 0);
            acc[nt] = __builtin_amdgcn_mfma_f32_16x16x32_bf16(alo, bh, acc[nt], 0, 0, 0);
            acc[nt] = __builtin_amdgcn_mfma_f32_16x16x32_bf16(ahi, bh, acc[nt], 0, 0, 0);
        }
    }
    #pragma unroll
    for (int nt = 0; nt < 4; ++nt)
        #pragma unroll
        for (int q = 0; q < 4; ++q) {
            int node = nb + lg * 4 + q;
            if (node < NN) out[node * HC + nt * 16 + lr] = acc[nt][q];
        }
}

// ---------------------------------------------------------------------------
extern "C" void kernel_launch(void* const* d_in, const int* in_sizes, int n_in,
                              void* d_out, int out_size, void* d_ws, size_t ws_size,
                              hipStream_t stream) {
    const float* x         = (const float*)d_in[0];
    const float* edge_attr = (const float*)d_in[1];
    const float* w_src     = (const float*)d_in[2];
    const float* w_dst     = (const float*)d_in[3];
    const float* w_edge    = (const float*)d_in[4];
    const float* w1        = (const float*)d_in[5];
    const float* gamma     = (const float*)d_in[6];
    const float* beta      = (const float*)d_in[7];
    const float* w2        = (const float*)d_in[8];
    const int*   eidx      = (const int*)d_in[9];    // [2][E], row 0 = src
    const int*   nbr       = (const int*)d_in[10];   // [N][K]

    float* ws   = (float*)d_ws;
    _Float16* srcPh = (_Float16*)ws;     // N*64 fp16 (permuted) = 1.6M floats
    float* dstf = ws + 3200000;          // N*64
    float* outf = ws + 6400000;          // N*64
    float* h    = ws + 9600000;          // N*128
    float* part = ws + 16000000;         // NBLK*256
    float* sb   = ws + 16250000;         // 256
    short* sp   = (short*)(ws + 16300000);
    short* pAhi = sp;                    // 16384 shorts
    short* pAlo = sp + 16384;
    short* p1hi = sp + 32768;            // 8192
    short* p1lo = sp + 40960;
    short* p2hi = sp + 49152;            // 8192
    short* p2lo = sp + 57344;
    short* pE   = sp + 65536;            // 2048

    hipLaunchKernelGGL(k_prep,          dim3(32),    dim3(256),  0, stream,
                       w_src, w_dst, w1, w2, w_edge,
                       pAhi, pAlo, p1hi, p1lo, p2hi, p2lo, pE);
    hipLaunchKernelGGL(k_lin1,          dim3(NBLK),  dim3(256),  0, stream,
                       x, pAhi, pAlo, srcPh, dstf);
    hipLaunchKernelGGL(k_edge_agg_mfma, dim3(GRID2), dim3(256),  0, stream,
                       srcPh, dstf, edge_attr, pE, eidx, nbr, outf);
    hipLaunchKernelGGL(k_lin2,          dim3(NBLK),  dim3(256),  0, stream,
                       outf, p1hi, p1lo, h, part);
    hipLaunchKernelGGL(k_bn_finalize,   dim3(1),     dim3(1024), 0, stream,
                       part, NBLK, gamma, beta, sb);
    hipLaunchKernelGGL(k_lin3,          dim3(NBLK),  dim3(256),  0, stream,
                       h, p2hi, p2lo, sb, (float*)d_out);
}

// Round 9
// 131.457 us; speedup vs baseline: 1.1834x; 1.0771x over previous
//
#include <hip/hip_runtime.h>
#include <hip/hip_bf16.h>
#include <float.h>

#define NN 50000
#define KNB 32
#define INC 128
#define HC 64
#define EDD 32
#define H2C 128
#define NBLK 782    // ceil(50000/64)

typedef __attribute__((ext_vector_type(8))) short bf16x8;
typedef __attribute__((ext_vector_type(4))) float f32x4;
typedef __attribute__((ext_vector_type(4))) _Float16 f16x4;

__device__ __forceinline__ short f2bf(float f) {
    unsigned u = __builtin_bit_cast(unsigned, f);
    u += 0x7fffu + ((u >> 16) & 1u);          // RTNE
    return (short)(u >> 16);
}
__device__ __forceinline__ float bf2f(short h) {
    unsigned u = ((unsigned)(unsigned short)h) << 16;
    return __builtin_bit_cast(float, u);
}

// pack 8 f32 -> bf16x8 with v_cvt_pk_bf16_f32 (RTNE, 4 instructions)
__device__ __forceinline__ bf16x8 pack8_bf16(const float* av) {
    union { unsigned u[4]; bf16x8 v; } r;
    #pragma unroll
    for (int w = 0; w < 4; ++w) {
        asm("v_cvt_pk_bf16_f32 %0, %1, %2"
            : "=v"(r.u[w]) : "v"(av[2 * w]), "v"(av[2 * w + 1]));
    }
    return r.v;
}

// ---------------------------------------------------------------------------
// K0: pre-convert weights to fragment-ordered bf16 buffers.
// ---------------------------------------------------------------------------
__global__ __launch_bounds__(256) void k_prep(
    const float* __restrict__ w_src, const float* __restrict__ w_dst,
    const float* __restrict__ w1, const float* __restrict__ w2,
    const float* __restrict__ w_edge,
    short* __restrict__ pAhi, short* __restrict__ pAlo,
    short* __restrict__ p1hi, short* __restrict__ p1lo,
    short* __restrict__ p2hi, short* __restrict__ p2lo,
    short* __restrict__ pE)
{
    const int tid = blockIdx.x * 256 + threadIdx.x;
    const int nT  = gridDim.x * 256;
    for (int idx = tid; idx < 16384; idx += nT) {
        int kt = (idx >> 12) & 3, nt = (idx >> 9) & 7, lane = (idx >> 3) & 63, j = idx & 7;
        int lr = lane & 15, lg = lane >> 4;
        int ch = nt * 16 + lr, k = kt * 32 + lg * 8 + j;
        float f = (ch < 64) ? w_src[ch * 128 + k] : w_dst[(ch - 64) * 128 + k];
        short hi = f2bf(f);
        pAhi[idx] = hi; pAlo[idx] = f2bf(f - bf2f(hi));
    }
    for (int idx = tid; idx < 8192; idx += nT) {
        int kt = (idx >> 12) & 1, nt = (idx >> 9) & 7, lane = (idx >> 3) & 63, j = idx & 7;
        int lr = lane & 15, lg = lane >> 4;
        int ch = nt * 16 + lr, k = kt * 32 + lg * 8 + j;
        float f = w1[ch * 64 + k];
        short hi = f2bf(f);
        p1hi[idx] = hi; p1lo[idx] = f2bf(f - bf2f(hi));
    }
    for (int idx = tid; idx < 8192; idx += nT) {
        int kt = (idx >> 11) & 3, nt = (idx >> 9) & 3, lane = (idx >> 3) & 63, j = idx & 7;
        int lr = lane & 15, lg = lane >> 4;
        int ch = nt * 16 + lr, k = kt * 32 + lg * 8 + j;
        float f = w2[ch * 128 + k];
        short hi = f2bf(f);
        p2hi[idx] = hi; p2lo[idx] = f2bf(f - bf2f(hi));
    }
    for (int idx = tid; idx < 2048; idx += nT) {
        int nt = (idx >> 9) & 3, lane = (idx >> 3) & 63, j = idx & 7;
        int lr = lane & 15, lg = lane >> 4;
        int ch = nt * 16 + lr, k = lg * 8 + j;
        pE[idx] = f2bf(w_edge[ch * EDD + k]);
    }
}

__device__ __forceinline__ void split8(const float* av, bf16x8& ahi, bf16x8& alo) {
    #pragma unroll
    for (int j = 0; j < 8; ++j) {
        short h = f2bf(av[j]);
        ahi[j] = h;
        alo[j] = f2bf(av[j] - bf2f(h));
    }
}

// ---------------------------------------------------------------------------
// K1 (MFMA): [srcPh|dstf] = x @ [w_src;w_dst].T ; srcPh stored PERMUTED fp16:
// srcPh[node*64 + lr*4 + nt] = src_ch[nt*16+lr]  (row = 128B)
// ---------------------------------------------------------------------------
__global__ __launch_bounds__(256) void k_lin1(
    const float* __restrict__ x, const short* __restrict__ pAhi,
    const short* __restrict__ pAlo, _Float16* __restrict__ srcPh,
    float* __restrict__ dstf)
{
    const int lane = threadIdx.x & 63, wave = threadIdx.x >> 6;
    const int lr = lane & 15, lg = lane >> 4;
    const int nb = blockIdx.x * 64 + wave * 16;
    const bf16x8* Bh = (const bf16x8*)pAhi;
    const bf16x8* Bl = (const bf16x8*)pAlo;
    int row = nb + lr; if (row > NN - 1) row = NN - 1;

    f32x4 acc[8];
    #pragma unroll
    for (int i = 0; i < 8; ++i) acc[i] = (f32x4){0.f, 0.f, 0.f, 0.f};

    #pragma unroll
    for (int kt = 0; kt < 4; ++kt) {
        const float* ap = x + (size_t)row * INC + kt * 32 + lg * 8;
        float4 a0 = *(const float4*)ap, a1 = *(const float4*)(ap + 4);
        float av[8] = {a0.x, a0.y, a0.z, a0.w, a1.x, a1.y, a1.z, a1.w};
        bf16x8 ahi, alo;
        split8(av, ahi, alo);
        #pragma unroll
        for (int nt = 0; nt < 8; ++nt) {
            bf16x8 bh = Bh[(kt * 8 + nt) * 64 + lane];
            bf16x8 bl = Bl[(kt * 8 + nt) * 64 + lane];
            acc[nt] = __builtin_amdgcn_mfma_f32_16x16x32_bf16(ahi, bl, acc[nt], 0, 0, 0);
            acc[nt] = __builtin_amdgcn_mfma_f32_16x16x32_bf16(alo, bh, acc[nt], 0, 0, 0);
            acc[nt] = __builtin_amdgcn_mfma_f32_16x16x32_bf16(ahi, bh, acc[nt], 0, 0, 0);
        }
    }
    #pragma unroll
    for (int nt = 0; nt < 8; ++nt)
        #pragma unroll
        for (int q = 0; q < 4; ++q) {
            int node = nb + lg * 4 + q;
            if (node < NN) {
                float v = acc[nt][q];
                if (nt < 4) srcPh[node * HC + lr * 4 + nt] = (_Float16)v;  // permuted fp16
                else        dstf[node * HC + (nt - 4) * 16 + lr] = v;
            }
        }
}

// ---------------------------------------------------------------------------
// K2 (MFMA, simple 1-node/wave, VALU-diet): edge projection + ReLU+eps +
// softmax aggregation. cvt_pk bf16 packing, rcp division, 32-bit gather
// offsets, fp16 gathers, no max-subtract.
// ---------------------------------------------------------------------------
__global__ __launch_bounds__(256) void k_edge_agg_mfma(
    const _Float16* __restrict__ srcPh, const float* __restrict__ dstf,
    const float* __restrict__ edge_attr, const short* __restrict__ pE,
    const int* __restrict__ esrc, const int* __restrict__ nbr,
    float* __restrict__ outf)
{
    const int lane = threadIdx.x & 63;
    const int wave = threadIdx.x >> 6;
    const int n    = blockIdx.x * 4 + wave;    // 12500 * 4 = 50000
    const int lr = lane & 15, lg = lane >> 4;

    // esrc slots for this lane's 8 edges (2 x int4)
    int4 s0 = *(const int4*)&esrc[n * KNB + lg * 4];
    int4 s1 = *(const int4*)&esrc[n * KNB + 16 + lg * 4];
    int nbv   = nbr[n * KNB + (lane & 31)];
    float d   = dstf[n * HC + lane];

    // B fragments (prepped bf16, raw 16B loads)
    const bf16x8* Bp = (const bf16x8*)pE;
    bf16x8 bfrag[4];
    #pragma unroll
    for (int nt = 0; nt < 4; ++nt) bfrag[nt] = Bp[nt * 64 + lane];

    // attr tile loads (nontemporal; single-use stream)
    const f32x4* ab = (const f32x4*)(edge_attr + (size_t)n * KNB * EDD);
    f32x4 at[4];
    #pragma unroll
    for (int mt = 0; mt < 2; ++mt) {
        int off = ((mt * 16 + lr) * EDD + lg * 8) >> 2;
        at[mt * 2]     = __builtin_nontemporal_load(ab + off);
        at[mt * 2 + 1] = __builtin_nontemporal_load(ab + off + 1);
    }

    // fp16 gathers, 32-bit offsets (idx*64 elements, +lr*4)
    int i0[4] = {s0.x, s0.y, s0.z, s0.w};
    int i1[4] = {s1.x, s1.y, s1.z, s1.w};
    f16x4 xj0[4], xj1[4];
    #pragma unroll
    for (int r = 0; r < 4; ++r)
        xj0[r] = *(const f16x4*)(srcPh + (((unsigned)i0[r] << 6) + lr * 4));
    #pragma unroll
    for (int r = 0; r < 4; ++r)
        xj1[r] = *(const f16x4*)(srcPh + (((unsigned)i1[r] << 6) + lr * 4));

    unsigned vmask = (unsigned)__ballot((lane < 32) && (nbv >= 0));

    // attr -> bf16 A-fragments via cvt_pk (RTNE, 4 ops per fragment)
    bf16x8 afrag[2];
    #pragma unroll
    for (int mt = 0; mt < 2; ++mt) {
        float av[8] = {at[mt*2][0], at[mt*2][1], at[mt*2][2], at[mt*2][3],
                       at[mt*2+1][0], at[mt*2+1][1], at[mt*2+1][2], at[mt*2+1][3]};
        afrag[mt] = pack8_bf16(av);
    }

    // projection: p[mt][nt][r] = P[16mt + lg*4 + r][16nt + lr]
    f32x4 p[2][4];
    #pragma unroll
    for (int mt = 0; mt < 2; ++mt)
        #pragma unroll
        for (int nt = 0; nt < 4; ++nt) {
            f32x4 z = {0.f, 0.f, 0.f, 0.f};
            p[mt][nt] = __builtin_amdgcn_mfma_f32_16x16x32_bf16(
                afrag[mt], bfrag[nt], z, 0, 0, 0);
        }

    // validity only for edges 16..31 (deg >= 16 guaranteed)
    float vf[4];
    #pragma unroll
    for (int r = 0; r < 4; ++r)
        vf[r] = ((vmask >> (16 + lg * 4 + r)) & 1u) ? 1.f : 0.f;

    // softmax-weighted mean (no max-subtract; eps folded to the end)
    float res[4];
    #pragma unroll
    for (int nt = 0; nt < 4; ++nt) {
        float se = 0.f, ws = 0.f;
        #pragma unroll
        for (int r = 0; r < 4; ++r) {
            float m = fmaxf(p[0][nt][r] + (float)xj0[r][nt], 0.f);
            float t = __expf(m);
            se += t;
            ws = fmaf(m, t, ws);
        }
        #pragma unroll
        for (int r = 0; r < 4; ++r) {
            float m = fmaxf(p[1][nt][r] + (float)xj1[r][nt], 0.f);
            float t = __expf(m) * vf[r];
            se += t;
            ws = fmaf(m, t, ws);
        }
        se += __shfl_xor(se, 16, 64); ws += __shfl_xor(ws, 16, 64);
        se += __shfl_xor(se, 32, 64); ws += __shfl_xor(ws, 32, 64);
        res[nt] = ws * __builtin_amdgcn_rcpf(se + 1e-16f);
    }

    float r01 = (lg & 1) ? res[1] : res[0];
    float r23 = (lg & 1) ? res[3] : res[2];
    float rr  = (lg & 2) ? r23 : r01;
    outf[n * HC + lane] = rr + d + 1e-7f;
}

// ---------------------------------------------------------------------------
// K3 (MFMA): h = out @ w1.T  [N,64]->[N,128]  + per-block BN partials.
// ---------------------------------------------------------------------------
__global__ __launch_bounds__(256) void k_lin2(
    const float* __restrict__ outf, const short* __restrict__ p1hi,
    const short* __restrict__ p1lo, float* __restrict__ h,
    float* __restrict__ partials)
{
    __shared__ float ps[128 * 16], pq[128 * 16];
    const int t = threadIdx.x;
    const int lane = t & 63, wave = t >> 6;
    const int lr = lane & 15, lg = lane >> 4;
    const int nb = blockIdx.x * 64 + wave * 16;
    const bf16x8* Bh = (const bf16x8*)p1hi;
    const bf16x8* Bl = (const bf16x8*)p1lo;
    int row = nb + lr; if (row > NN - 1) row = NN - 1;

    f32x4 acc[8];
    #pragma unroll
    for (int i = 0; i < 8; ++i) acc[i] = (f32x4){0.f, 0.f, 0.f, 0.f};

    #pragma unroll
    for (int kt = 0; kt < 2; ++kt) {
        const float* ap = outf + (size_t)row * HC + kt * 32 + lg * 8;
        float4 a0 = *(const float4*)ap, a1 = *(const float4*)(ap + 4);
        float av[8] = {a0.x, a0.y, a0.z, a0.w, a1.x, a1.y, a1.z, a1.w};
        bf16x8 ahi, alo;
        split8(av, ahi, alo);
        #pragma unroll
        for (int nt = 0; nt < 8; ++nt) {
            bf16x8 bh = Bh[(kt * 8 + nt) * 64 + lane];
            bf16x8 bl = Bl[(kt * 8 + nt) * 64 + lane];
            acc[nt] = __builtin_amdgcn_mfma_f32_16x16x32_bf16(ahi, bl, acc[nt], 0, 0, 0);
            acc[nt] = __builtin_amdgcn_mfma_f32_16x16x32_bf16(alo, bh, acc[nt], 0, 0, 0);
            acc[nt] = __builtin_amdgcn_mfma_f32_16x16x32_bf16(ahi, bh, acc[nt], 0, 0, 0);
        }
    }

    #pragma unroll
    for (int nt = 0; nt < 8; ++nt) {
        float s = 0.f, q = 0.f;
        #pragma unroll
        for (int qq = 0; qq < 4; ++qq) {
            int node = nb + lg * 4 + qq;
            float v = acc[nt][qq];
            if (node < NN) {
                h[node * H2C + nt * 16 + lr] = v;
                s += v;
                q += v * v;
            }
        }
        ps[(nt * 16 + lr) * 16 + wave * 4 + lg] = s;
        pq[(nt * 16 + lr) * 16 + wave * 4 + lg] = q;
    }
    __syncthreads();
    if (t < 128) {
        float s = 0.f, q = 0.f;
        #pragma unroll
        for (int i = 0; i < 16; ++i) { s += ps[t * 16 + i]; q += pq[t * 16 + i]; }
        partials[blockIdx.x * 256 + t]       = s;
        partials[blockIdx.x * 256 + 128 + t] = q;
    }
}

// ---------------------------------------------------------------------------
// K4: reduce partials -> BN scale/bias (1024 threads, vectorized).
// ---------------------------------------------------------------------------
__global__ __launch_bounds__(1024) void k_bn_finalize(
    const float* __restrict__ partials, int nblk,
    const float* __restrict__ gamma, const float* __restrict__ beta,
    float* __restrict__ sb)
{
    const int t = threadIdx.x;
    const int f = t & 63;
    const int g = t >> 6;

    float4 acc = {0.f, 0.f, 0.f, 0.f};
    for (int b = g; b < nblk; b += 16) {
        float4 v = *(const float4*)&partials[b * 256 + f * 4];
        acc.x += v.x; acc.y += v.y; acc.z += v.z; acc.w += v.w;
    }

    __shared__ __align__(16) float4 red[16][64];
    red[g][f] = acc;
    __syncthreads();
    #pragma unroll
    for (int s = 8; s > 0; s >>= 1) {
        if (g < s) {
            float4 o = red[g + s][f];
            acc.x += o.x; acc.y += o.y; acc.z += o.z; acc.w += o.w;
            red[g][f] = acc;
        }
        __syncthreads();
    }

    if (t < 128) {
        const float* row = (const float*)&red[0][0];
        float s = row[t];
        float q = row[128 + t];
        float mean = s / (float)NN;
        float var  = q / (float)NN - mean * mean;
        float scale = gamma[t] * rsqrtf(var + 1e-5f);
        float bias  = beta[t] - mean * scale;
        sb[t]       = scale;
        sb[128 + t] = bias;
    }
}

// ---------------------------------------------------------------------------
// K5 (MFMA): out2 = relu(h*scale+bias) @ w2.T  [N,128]->[N,64]
// ---------------------------------------------------------------------------
__global__ __launch_bounds__(256) void k_lin3(
    const float* __restrict__ h, const short* __restrict__ p2hi,
    const short* __restrict__ p2lo, const float* __restrict__ sb,
    float* __restrict__ out)
{
    const int lane = threadIdx.x & 63, wave = threadIdx.x >> 6;
    const int lr = lane & 15, lg = lane >> 4;
    const int nb = blockIdx.x * 64 + wave * 16;
    const bf16x8* Bh = (const bf16x8*)p2hi;
    const bf16x8* Bl = (const bf16x8*)p2lo;
    int row = nb + lr; if (row > NN - 1) row = NN - 1;

    f32x4 acc[4];
    #pragma unroll
    for (int i = 0; i < 4; ++i) acc[i] = (f32x4){0.f, 0.f, 0.f, 0.f};

    #pragma unroll
    for (int kt = 0; kt < 4; ++kt) {
        const int k0 = kt * 32 + lg * 8;
        float4 sc0 = *(const float4*)&sb[k0],       sc1 = *(const float4*)&sb[k0 + 4];
        float4 bi0 = *(const float4*)&sb[128 + k0], bi1 = *(const float4*)&sb[128 + k0 + 4];
        const float* ap = h + (size_t)row * H2C + k0;
        float4 a0 = *(const float4*)ap, a1 = *(const float4*)(ap + 4);
        float av[8]  = {a0.x, a0.y, a0.z, a0.w, a1.x, a1.y, a1.z, a1.w};
        float scv[8] = {sc0.x, sc0.y, sc0.z, sc0.w, sc1.x, sc1.y, sc1.z, sc1.w};
        float biv[8] = {bi0.x, bi0.y, bi0.z, bi0.w, bi1.x, bi1.y, bi1.z, bi1.w};
        float rv[8];
        #pragma unroll
        for (int j = 0; j < 8; ++j) {
            float v = av[j] * scv[j] + biv[j];
            rv[j] = v > 0.f ? v : 0.f;
        }
        bf16x8 ahi, alo;
        split8(rv, ahi, alo);
        #pragma unroll
        for (int nt = 0; nt < 4; ++nt) {
            bf16x8 bh = Bh[(kt * 4 + nt) * 64 + lane];
            bf16x8 bl = Bl[(kt * 4 + nt) * 64 + lane];
            acc[nt] = __builtin_amdgcn_mfma_f32_16x16x32_bf16(ahi, bl, acc[nt], 0, 0, 0);
            acc[nt] = __builtin_amdgcn_mfma_f32_16x16x32_bf16(alo, bh, acc[nt], 0, 0, 0);
            acc[nt] = __builtin_amdgcn_mfma_f32_16x16x32_bf16(ahi, bh, acc[nt], 0, 0, 0);
        }
    }
    #pragma unroll
    for (int nt = 0; nt < 4; ++nt)
        #pragma unroll
        for (int q = 0; q < 4; ++q) {
            int node = nb + lg * 4 + q;
            if (node < NN) out[node * HC + nt * 16 + lr] = acc[nt][q];
        }
}

// ---------------------------------------------------------------------------
extern "C" void kernel_launch(void* const* d_in, const int* in_sizes, int n_in,
                              void* d_out, int out_size, void* d_ws, size_t ws_size,
                              hipStream_t stream) {
    const float* x         = (const float*)d_in[0];
    const float* edge_attr = (const float*)d_in[1];
    const float* w_src     = (const float*)d_in[2];
    const float* w_dst     = (const float*)d_in[3];
    const float* w_edge    = (const float*)d_in[4];
    const float* w1        = (const float*)d_in[5];
    const float* gamma     = (const float*)d_in[6];
    const float* beta      = (const float*)d_in[7];
    const float* w2        = (const float*)d_in[8];
    const int*   eidx      = (const int*)d_in[9];    // [2][E], row 0 = src
    const int*   nbr       = (const int*)d_in[10];   // [N][K]

    float* ws   = (float*)d_ws;
    _Float16* srcPh = (_Float16*)ws;     // N*64 fp16 (permuted)
    float* dstf = ws + 3200000;          // N*64
    float* outf = ws + 6400000;          // N*64
    float* h    = ws + 9600000;          // N*128
    float* part = ws + 16000000;         // NBLK*256
    float* sb   = ws + 16250000;         // 256
    short* sp   = (short*)(ws + 16300000);
    short* pAhi = sp;                    // 16384 shorts
    short* pAlo = sp + 16384;
    short* p1hi = sp + 32768;            // 8192
    short* p1lo = sp + 40960;
    short* p2hi = sp + 49152;            // 8192
    short* p2lo = sp + 57344;
    short* pE   = sp + 65536;            // 2048

    hipLaunchKernelGGL(k_prep,          dim3(32),    dim3(256),  0, stream,
                       w_src, w_dst, w1, w2, w_edge,
                       pAhi, pAlo, p1hi, p1lo, p2hi, p2lo, pE);
    hipLaunchKernelGGL(k_lin1,          dim3(NBLK),  dim3(256),  0, stream,
                       x, pAhi, pAlo, srcPh, dstf);
    hipLaunchKernelGGL(k_edge_agg_mfma, dim3(12500), dim3(256),  0, stream,
                       srcPh, dstf, edge_attr, pE, eidx, nbr, outf);
    hipLaunchKernelGGL(k_lin2,          dim3(NBLK),  dim3(256),  0, stream,
                       outf, p1hi, p1lo, h, part);
    hipLaunchKernelGGL(k_bn_finalize,   dim3(1),     dim3(1024), 0, stream,
                       part, NBLK, gamma, beta, sb);
    hipLaunchKernelGGL(k_lin3,          dim3(NBLK),  dim3(256),  0, stream,
                       h, p2hi, p2lo, sb, (float*)d_out);
}